// Round 2
// baseline (809.331 us; speedup 1.0000x reference)
//
#include <hip/hip_runtime.h>
#include <hip/hip_bf16.h>
#include <stdint.h>

// ---------------- problem constants ----------------
#define N_TOK 8192
#define DIM   1024
#define FF    4096
#define NEXP  8
#define MAXTILES 72   // sum ceil(ce/256) <= 16384/256 + 7 = 71

// ---------------- workspace layout (bytes) ----------------
#define OFF_COUNTS 0ull
#define OFF_NTILES 64ull
#define OFF_TABLE  4096ull            // 72 * 16
#define OFF_IDX    16384ull           // 8*8192*4 = 262144
#define OFF_GATE   278528ull          // 262144
#define OFF_XB     1048576ull         // 8192*1024*2 = 16,777,216
#define OFF_H      17825792ull        // 18432*4096*2 = 150,994,944
#define OFF_WB     168820736ull       // 8*4096*1024*2 = 67,108,864 (w1b, then w2b aliased)
#define NEED       235929600ull

typedef __attribute__((ext_vector_type(8))) short s16x8;   // 8 bf16 MFMA frag
typedef __attribute__((ext_vector_type(4))) float f32x4;   // MFMA accum

__device__ __forceinline__ unsigned short f2bf(float f) {
  union { float f; unsigned int u; } v; v.f = f;
  unsigned int u = v.u;
  unsigned int r = (u + 0x7FFFu + ((u >> 16) & 1u)) >> 16;  // RNE
  return (unsigned short)r;
}

// gelu: 0.5*x*(1+erf(x/sqrt2)), erf via A&S 7.1.26 (|err|<1.5e-7)
__device__ __forceinline__ float gelu_f(float x) {
  float s = x * 0.70710678118654752f;
  float a = fabsf(s);
  float t = 1.0f / fmaf(0.3275911f, a, 1.0f);
  float p = t * fmaf(t, fmaf(t, fmaf(t, fmaf(t, 1.061405429f, -1.453152027f),
                                     1.421413741f), -0.284496736f), 0.254829592f);
  float e = __expf(-a * a);
  float erf_a = 1.0f - p * e;
  float erf_s = (s >= 0.0f) ? erf_a : -erf_a;
  return 0.5f * x * (1.0f + erf_s);
}

// async global -> LDS, 16B per lane (dest = wave-uniform base + lane*16)
__device__ __forceinline__ void load_lds16(const void* g, void* l) {
  __builtin_amdgcn_global_load_lds(
      (const __attribute__((address_space(1))) unsigned int*)g,
      (__attribute__((address_space(3))) unsigned int*)l, 16, 0, 0);
}

// ---------------- f32 -> bf16 bulk convert ----------------
__global__ __launch_bounds__(256) void cvt_f32_bf16(const float4* __restrict__ in,
                                                    ushort4* __restrict__ out, int n4) {
  int i = blockIdx.x * 256 + threadIdx.x;
  int stride = gridDim.x * 256;
  for (; i < n4; i += stride) {
    float4 f = in[i];
    ushort4 u;
    u.x = f2bf(f.x); u.y = f2bf(f.y); u.z = f2bf(f.z); u.w = f2bf(f.w);
    out[i] = u;
  }
}

// ---------------- router: 1 wave per token ----------------
__global__ __launch_bounds__(256) void router_kernel(
    const float* __restrict__ x, const float* __restrict__ rw,
    int* __restrict__ counts, int* __restrict__ idx_list, float* __restrict__ gate_list) {
  int wid = threadIdx.x >> 6;
  int lane = threadIdx.x & 63;
  int token = blockIdx.x * 4 + wid;

  const float4* xr = (const float4*)(x + (size_t)token * DIM);
  float p[NEXP];
#pragma unroll
  for (int e = 0; e < NEXP; ++e) p[e] = 0.f;
#pragma unroll
  for (int c = 0; c < 4; ++c) {
    float4 xv = xr[c * 64 + lane];
#pragma unroll
    for (int e = 0; e < NEXP; ++e) {
      float4 wv = ((const float4*)(rw + (size_t)e * DIM))[c * 64 + lane];
      p[e] += xv.x * wv.x + xv.y * wv.y + xv.z * wv.z + xv.w * wv.w;
    }
  }
#pragma unroll
  for (int e = 0; e < NEXP; ++e) {
    float v = p[e];
#pragma unroll
    for (int off = 32; off > 0; off >>= 1) v += __shfl_xor(v, off, 64);
    p[e] = v;
  }
  if (lane == 0) {
    int e0 = 0; float v0 = p[0];
#pragma unroll
    for (int e = 1; e < NEXP; ++e) if (p[e] > v0) { v0 = p[e]; e0 = e; }
    int e1 = (e0 == 0) ? 1 : 0; float v1 = -3.4e38f;
#pragma unroll
    for (int e = 0; e < NEXP; ++e) if (e != e0 && p[e] > v1) { v1 = p[e]; e1 = e; }
    float ex = __expf(v1 - v0);
    float g0 = 1.0f / (1.0f + ex);
    float g1 = ex / (1.0f + ex);
    int p0 = atomicAdd(&counts[e0], 1);
    idx_list[e0 * N_TOK + p0] = token;
    gate_list[e0 * N_TOK + p0] = g0;
    int p1 = atomicAdd(&counts[e1], 1);
    idx_list[e1 * N_TOK + p1] = token;
    gate_list[e1 * N_TOK + p1] = g1;
  }
}

// ---------------- schedule: counts -> 256-row tile table ----------------
__global__ void schedule_kernel(const int* __restrict__ counts, int4* __restrict__ table,
                                int* __restrict__ ntiles) {
  if (threadIdx.x == 0 && blockIdx.x == 0) {
    int tt = 0, gb = 0;
    for (int e = 0; e < NEXP; ++e) {
      int c = counts[e];
      int t = (c + 255) >> 8;
      for (int i = 0; i < t; ++i) { table[tt] = make_int4(e, i << 8, gb + (i << 8), 0); tt++; }
      gb += t << 8;
    }
    *ntiles = tt;
  }
}

// ---------------- grouped GEMM: 256x256 tile, BK=32, 8 waves, BUFS-deep pipeline ----
// EPI==1: H[gbase+r] = gelu(A_gathered @ W^T) (bf16), A rows gathered via idx_list.
// EPI==2: atomicAdd(Out[token], gate * (H @ W^T)), A rows = h at gbase+r.
// Pipeline: stage tile t+BUFS-1 during tile t (issue strictly after all reads of the
// buffer's previous occupant completed -> race-free). Boundary wait: vmcnt(4*after)
// where after = #tiles staged beyond t (<= BUFS-2); never drains to 0 mid-loop.
template <int KDIM, int BUFS, int EPI>
__global__ __launch_bounds__(512, 2) void moe_gemm8(
    const unsigned short* __restrict__ Abase, const unsigned short* __restrict__ Bb,
    unsigned short* __restrict__ Hout, float* __restrict__ Out,
    const int* __restrict__ idx_list, const float* __restrict__ gate_list,
    const int* __restrict__ counts, const int4* __restrict__ table,
    const int* __restrict__ n_tiles) {
  if ((int)blockIdx.y >= *n_tiles) return;
  int4 te = table[blockIdx.y];
  const int e = te.x, row_start = te.y, gbase = te.z;
  const int ce = counts[e];
  const int tid = threadIdx.x;
  const int wid = tid >> 6, lane = tid & 63;
  const int colT = blockIdx.x * 256;

  extern __shared__ char smem[];
  unsigned short* As = (unsigned short*)smem;          // [BUFS][256][32]
  unsigned short* Bs = As + BUFS * 256 * 32;           // [BUFS][256][32]

  // --- staging source offsets (bytes): thread covers 2 rows (j*128+tid/4), 8 elems each
  const int srow = tid >> 2;
  const int scol = (tid & 3) * 8;
  size_t aoff[2], boff[2];
#pragma unroll
  for (int j = 0; j < 2; ++j) {
    int r = j * 128 + srow;
    if constexpr (EPI == 1) {
      int rl = row_start + r; if (rl >= ce) rl = ce - 1;   // clamp padded rows
      int tok = idx_list[e * N_TOK + rl];
      aoff[j] = ((size_t)tok * KDIM + scol) * 2;
    } else {
      aoff[j] = ((size_t)(gbase + r) * KDIM + scol) * 2;
    }
    boff[j] = ((size_t)e * FF * DIM + (size_t)(colT + r) * KDIM + scol) * 2;
  }
  const char* Ag = (const char*)Abase;
  const char* Bg = (const char*)Bb;
  const int NT = KDIM / 32;

  auto stageA = [&](int t2) {
    char* dst = (char*)(As + (t2 & (BUFS - 1)) * 8192) + tid * 16;
    size_t ko = (size_t)t2 * 64;
    load_lds16(Ag + aoff[0] + ko, dst);
    load_lds16(Ag + aoff[1] + ko, dst + 8192);
  };
  auto stageB = [&](int t2) {
    char* dst = (char*)(Bs + (t2 & (BUFS - 1)) * 8192) + tid * 16;
    size_t ko = (size_t)t2 * 64;
    load_lds16(Bg + boff[0] + ko, dst);
    load_lds16(Bg + boff[1] + ko, dst + 8192);
  };

  // --- fragment read bases
  const int wr = wid >> 2;          // 0..1 : row half (128 rows)
  const int wcn = wid & 3;          // 0..3 : col quarter (64 cols)
  const int r16 = lane & 15, kg = lane >> 4;
  const unsigned short* Arow = As + (wr * 128 + r16) * 32 + kg * 8;
  const unsigned short* Brow = Bs + (wcn * 64 + r16) * 32 + kg * 8;

  f32x4 acc[8][4] = {};

  // --- prologue: stage tiles 0..BUFS-2
#pragma unroll
  for (int t = 0; t < BUFS - 1; ++t) { stageA(t); stageB(t); }

  for (int t = 0; t < NT; ++t) {
    // boundary: ensure tile t's 4 half-stages landed; leave future tiles in flight
    int after = NT - 1 - t; if (after > BUFS - 2) after = BUFS - 2;
    if (after >= 2)      asm volatile("s_waitcnt vmcnt(8)" ::: "memory");
    else if (after == 1) asm volatile("s_waitcnt vmcnt(4)" ::: "memory");
    else                 asm volatile("s_waitcnt vmcnt(0)" ::: "memory");
    asm volatile("s_barrier" ::: "memory");

    const int buf = t & (BUFS - 1);
    const unsigned short* Ap = Arow + buf * 8192;
    const unsigned short* Bp = Brow + buf * 8192;

    // ---- phase 0: frags m0..3 + all B, stage A of tile t+BUFS-1, 16 MFMA
    s16x8 a[4], b[4];
#pragma unroll
    for (int n = 0; n < 4; ++n) b[n] = *(const s16x8*)(Bp + n * 512);
#pragma unroll
    for (int m = 0; m < 4; ++m) a[m] = *(const s16x8*)(Ap + m * 512);
    if (t + BUFS - 1 < NT) stageA(t + BUFS - 1);
    asm volatile("s_barrier" ::: "memory");
    __builtin_amdgcn_s_setprio(1);
#pragma unroll
    for (int m = 0; m < 4; ++m)
#pragma unroll
      for (int n = 0; n < 4; ++n)
        acc[m][n] = __builtin_amdgcn_mfma_f32_16x16x32_bf16(a[m], b[n], acc[m][n], 0, 0, 0);
    __builtin_amdgcn_s_setprio(0);
    asm volatile("s_barrier" ::: "memory");

    // ---- phase 1: frags m4..7, stage B of tile t+BUFS-1, 16 MFMA
#pragma unroll
    for (int m = 0; m < 4; ++m) a[m] = *(const s16x8*)(Ap + (m + 4) * 512);
    if (t + BUFS - 1 < NT) stageB(t + BUFS - 1);
    asm volatile("s_barrier" ::: "memory");
    __builtin_amdgcn_s_setprio(1);
#pragma unroll
    for (int m = 0; m < 4; ++m)
#pragma unroll
      for (int n = 0; n < 4; ++n)
        acc[m + 4][n] = __builtin_amdgcn_mfma_f32_16x16x32_bf16(a[m], b[n], acc[m + 4][n], 0, 0, 0);
    __builtin_amdgcn_s_setprio(0);
  }

  // ---- epilogue
  if constexpr (EPI == 1) {
#pragma unroll
    for (int m = 0; m < 8; ++m) {
      const int row_l = wr * 128 + m * 16 + kg * 4;
#pragma unroll
      for (int j = 0; j < 4; ++j) {
        size_t hrow = (size_t)(gbase + row_l + j) * FF + colT + wcn * 64;
#pragma unroll
        for (int n = 0; n < 4; ++n)
          Hout[hrow + n * 16 + r16] = f2bf(gelu_f(acc[m][n][j]));
      }
    }
  } else {
#pragma unroll
    for (int m = 0; m < 8; ++m) {
      const int row_l = wr * 128 + m * 16 + kg * 4;
#pragma unroll
      for (int j = 0; j < 4; ++j) {
        int r = row_start + row_l + j;
        if (r < ce) {
          int tok = idx_list[e * N_TOK + r];
          float g = gate_list[e * N_TOK + r];
          float* orow = Out + (size_t)tok * DIM + colT + wcn * 64;
#pragma unroll
          for (int n = 0; n < 4; ++n)
            atomicAdd(&orow[n * 16 + r16], acc[m][n][j] * g);
        }
      }
    }
  }
}

// ---------------- launch ----------------
extern "C" void kernel_launch(void* const* d_in, const int* in_sizes, int n_in,
                              void* d_out, int out_size, void* d_ws, size_t ws_size,
                              hipStream_t stream) {
  const float* x  = (const float*)d_in[0];
  const float* rw = (const float*)d_in[1];
  const float* w1 = (const float*)d_in[2];
  const float* w2 = (const float*)d_in[3];
  float* out = (float*)d_out;
  char* ws = (char*)d_ws;
  if (ws_size < NEED) return;

  int*   counts    = (int*)(ws + OFF_COUNTS);
  int*   ntiles    = (int*)(ws + OFF_NTILES);
  int4*  table     = (int4*)(ws + OFF_TABLE);
  int*   idx_list  = (int*)(ws + OFF_IDX);
  float* gate_list = (float*)(ws + OFF_GATE);
  unsigned short* xb = (unsigned short*)(ws + OFF_XB);
  unsigned short* h  = (unsigned short*)(ws + OFF_H);
  unsigned short* wb = (unsigned short*)(ws + OFF_WB);

  // opt-in to 128 KiB dynamic LDS for the 4-buffer pipeline; fallback to 2-buffer/64K
  bool deep = true;
  if (hipFuncSetAttribute(reinterpret_cast<const void*>(&moe_gemm8<DIM, 4, 1>),
                          hipFuncAttributeMaxDynamicSharedMemorySize, 131072) != hipSuccess)
    deep = false;
  if (hipFuncSetAttribute(reinterpret_cast<const void*>(&moe_gemm8<FF, 4, 2>),
                          hipFuncAttributeMaxDynamicSharedMemorySize, 131072) != hipSuccess)
    deep = false;

  hipMemsetAsync(d_out, 0, (size_t)N_TOK * DIM * sizeof(float), stream);
  hipMemsetAsync(ws, 0, 256, stream);  // counts + ntiles

  cvt_f32_bf16<<<1024, 256, 0, stream>>>((const float4*)x, (ushort4*)xb, N_TOK * DIM / 4);
  router_kernel<<<N_TOK / 4, 256, 0, stream>>>(x, rw, counts, idx_list, gate_list);
  schedule_kernel<<<1, 64, 0, stream>>>(counts, table, ntiles);

  // w1 -> bf16, GEMM1, then w2 -> bf16 into the SAME buffer (stream-ordered), GEMM2
  cvt_f32_bf16<<<2048, 256, 0, stream>>>((const float4*)w1, (ushort4*)wb, NEXP * FF * DIM / 4);
  if (deep) {
    moe_gemm8<DIM, 4, 1><<<dim3(FF / 256, MAXTILES), 512, 131072, stream>>>(
        xb, wb, h, nullptr, idx_list, gate_list, counts, table, ntiles);
  } else {
    moe_gemm8<DIM, 2, 1><<<dim3(FF / 256, MAXTILES), 512, 65536, stream>>>(
        xb, wb, h, nullptr, idx_list, gate_list, counts, table, ntiles);
  }
  cvt_f32_bf16<<<2048, 256, 0, stream>>>((const float4*)w2, (ushort4*)wb, NEXP * FF * DIM / 4);
  if (deep) {
    moe_gemm8<FF, 4, 2><<<dim3(DIM / 256, MAXTILES), 512, 131072, stream>>>(
        h, wb, nullptr, out, idx_list, gate_list, counts, table, ntiles);
  } else {
    moe_gemm8<FF, 2, 2><<<dim3(DIM / 256, MAXTILES), 512, 65536, stream>>>(
        h, wb, nullptr, out, idx_list, gate_list, counts, table, ntiles);
  }
}